// Round 4
// baseline (277.409 us; speedup 1.0000x reference)
//
#include <hip/hip_runtime.h>
#include <cmath>

#define PI_F 3.14159265358979323846f
#define NTOK 128
#define NPIX 16384
#define NHEADS 16
#define NBLK 1024u

__device__ __forceinline__ void block_reduce2(float& a, float& b){
  __shared__ float sa[4], sb[4];
  __syncthreads();
  for (int o=32;o>0;o>>=1){ a += __shfl_down(a,o); b += __shfl_down(b,o); }
  int w = threadIdx.x>>6, l = threadIdx.x&63;
  if (l==0){ sa[w]=a; sb[w]=b; }
  __syncthreads();
  a = sa[0]+sa[1]+sa[2]+sa[3];
  b = sb[0]+sb[1]+sb[2]+sb[3];
}

__device__ __forceinline__ float block_reduce1(float a){
  __shared__ float sa[4];
  __syncthreads();
  for (int o=32;o>0;o>>=1) a += __shfl_down(a,o);
  int w = threadIdx.x>>6, l = threadIdx.x&63;
  if (l==0) sa[w]=a;
  __syncthreads();
  return sa[0]+sa[1]+sa[2]+sa[3];
}

__device__ __forceinline__ float gelu_f(float y){
  return 0.5f*y*(1.f + erff(y*0.70710678118f));
}

// ---- software global barrier (one-shot counter per barrier) ----------------
__device__ __forceinline__ void gbar(unsigned* cnt){
  __syncthreads();
  __threadfence();
  if (threadIdx.x==0){
    atomicAdd(cnt, 1u);
    while (__hip_atomic_load(cnt, __ATOMIC_RELAXED, __HIP_MEMORY_SCOPE_AGENT) < NBLK)
      __builtin_amdgcn_s_sleep(2);
  }
  __syncthreads();
  __threadfence();
}

// ---- per-token scalars -----------------------------------------------------
__device__ __forceinline__ void affine_from(const float* ps, float g, float bb, int t,
                                            float& a, float& b0){
  float sum=0.f,sq=0.f;
  #pragma unroll
  for (int s=0;s<8;s++){ const float* p=ps+((size_t)t*8+s)*2; sum+=p[0]; sq+=p[1]; }
  const float iN=1.f/NPIX;
  float mu=sum*iN, var=sq*iN-mu*mu;
  a=rsqrtf(var+1e-5f)*g;
  b0=bb-mu*a;
}
__device__ __forceinline__ void scalA_from(const float* psA, float ag, float n2g, int t,
                                           float& muZ, float& aA, float& a0){
  float sum=0.f,sq=0.f;
  #pragma unroll
  for (int s=0;s<16;s++){ const float* p=psA+((size_t)t*16+s)*2; sum+=p[0]; sq+=p[1]; }
  const float iN=1.f/NPIX;
  muZ=sum*iN; float var=sq*iN-muZ*muZ;
  float inv=rsqrtf(var+1e-5f);
  aA=inv*ag;
  float var2=aA*aA*var;
  a0=aA*rsqrtf(var2+1e-5f)*n2g;
}
__device__ __forceinline__ void scalB_from(const float* psB, float mng1, int t,
                                           float& mu1, float& c1){
  float sum=0.f,sq=0.f;
  #pragma unroll
  for (int s=0;s<16;s++){ const float* p=psB+((size_t)t*16+s)*2; sum+=p[0]; sq+=p[1]; }
  const float iN=1.f/NPIX;
  mu1=sum*iN; float var=sq*iN-mu1*mu1;
  c1=rsqrtf(var+1e-5f)*mng1;
}
__device__ __forceinline__ void scalC_from(const float* psC, float mng2, float K, float sw,
                                           float outg, int t,
                                           float& mu2f, float& c2, float& mu3, float& c3){
  float sf=0.f,sfsq=0.f,sm=0.f,smsq=0.f,sx=0.f;
  #pragma unroll
  for (int s=0;s<16;s++){
    const float* p=psC+((size_t)t*16+s)*5;
    sf+=p[0]; sfsq+=p[1]; sm+=p[2]; smsq+=p[3]; sx+=p[4];
  }
  const float iN=1.f/NPIX;
  mu2f=sf*iN; float var2=sfsq*iN-mu2f*mu2f;
  c2=rsqrtf(var2+1e-5f)*mng2;
  float Em1=sm*iN, Em1sq=smsq*iN, Exm=sx*iN;
  float Em2=K+sw*Em1;
  float Em2sq = c2*c2*var2 + sw*sw*Em1sq + K*K
              + 2.f*c2*sw*(Exm - mu2f*Em1) + 2.f*K*sw*Em1;
  float var_m2=Em2sq-Em2*Em2;
  mu3=Em2;
  c3=rsqrtf(var_m2+1e-5f)*outg;
}

// ============================ stage bodies ==================================

// ---- scol: column DFT of RAW x (units 0..1023, radix 16x8) + stats (1024..2047)
__device__ __forceinline__ void st_scol(int bx, float* sh, const float* x,
                                        float* A, float* pstat){
  if (bx<1024){
    float* rows=sh; float* S1=sh+2048; float* tw=sh+4640;
    int base = bx*16;
    for (int i=threadIdx.x;i<2048;i+=256) rows[i] = x[(size_t)base*128 + i];
    for (int q=threadIdx.x;q<128;q+=256){ float sn,cs; sincosf(-(2.f*PI_F/128.f)*(float)q,&sn,&cs); tw[q*2]=cs; tw[q*2+1]=sn; }
    __syncthreads();
    for (int e=threadIdx.x;e<1280;e+=256){
      int r=e/80, q=e%80, w0=q/5, k=q%5;
      const float* y=rows+r*128+w0;
      float re=0.f, im=0.f;
      #pragma unroll
      for (int w1=0;w1<8;w1++){
        int p=(16*k*w1)&127;
        float v=y[w1*16];
        re+=v*tw[p*2]; im+=v*tw[p*2+1];
      }
      float* o=S1+r*162+q*2; o[0]=re; o[1]=im;
    }
    __syncthreads();
    for (int e=threadIdx.x;e<528;e+=256){
      int r=e/33, c=e%33;
      int m=c&7; int ks=m; float sg=1.f;
      if (m>4){ ks=8-m; sg=-1.f; }
      const float* Sp=S1+r*162+ks*2;
      float re=0.f, im=0.f;
      #pragma unroll
      for (int w0=0;w0<16;w0++){
        int p=(c*w0)&127;
        float cr=tw[p*2], ci=tw[p*2+1];
        float sr=Sp[w0*10], si=sg*Sp[w0*10+1];
        re += sr*cr - si*ci;
        im += sr*ci + si*cr;
      }
      float* o=A+((size_t)(base+r)*33+c)*2; o[0]=re; o[1]=im;
    }
  } else {
    int u=bx-1024; int t=u>>3, slab=u&7;
    const float* xs = x + (size_t)t*NPIX + slab*2048;
    float sum=0.f, sq=0.f;
    for (int i=threadIdx.x;i<2048;i+=256){ float v=xs[i]; sum+=v; sq+=v*v; }
    block_reduce2(sum,sq);
    if (threadIdx.x==0){ float* o=pstat+((size_t)t*8+slab)*2; o[0]=sum; o[1]=sq; }
  }
}

// ---- rowfft64 (radix 16x8): units 0..383 (s=u%128, cg2=u/128) --------------
__device__ __forceinline__ void st_row64(int u, float* sh, const float* A,
                          const float* pstat0, const float* n1g, const float* n1b,
                          float* X64, float* X64h){
  int s=u%128, cg2=u/128;
  int c0=cg2*11;
  float* a=sh;            // 2816
  float* S1=sh+2816;      // 3190
  float* S=sh+6006;       // 1408
  float* tw=sh+7414;      // 256
  for (int i=threadIdx.x;i<128*22;i+=256){
    int r=i/22, q=i%22;
    a[(r*11+(q>>1))*2+(q&1)] = A[((size_t)(s*128+r)*33 + c0)*2 + q];
  }
  for (int q=threadIdx.x;q<128;q+=256){ float sn,cs; sincosf(-(2.f*PI_F/128.f)*(float)q,&sn,&cs); tw[q*2]=cs; tw[q*2+1]=sn; }
  float af,b0; affine_from(pstat0, n1g[0], n1b[0], s, af, b0);
  __syncthreads();
  for (int e=threadIdx.x;e<1408;e+=256){
    int cl=e>>7, q=e&127, h0=q>>3, k=q&7;
    float re=0.f, im=0.f;
    #pragma unroll
    for (int h1=0;h1<8;h1++){
      int p=(16*k*h1)&127;
      float cr=tw[p*2], ci=tw[p*2+1];
      const float* ap=a+((h0+16*h1)*11+cl)*2;
      float ar=ap[0], ai=ap[1];
      re += ar*cr - ai*ci;
      im += ar*ci + ai*cr;
    }
    float* o=S1+cl*290+h0*18+k*2; o[0]=re; o[1]=im;
  }
  __syncthreads();
  const float sc=1.f/16384.f;
  for (int e=threadIdx.x;e<64*11;e+=256){
    int i2=e/11, cl=e%11;
    int r=(i2<32)? i2 : i2+64;
    int k=r&7;
    const float* Sp=S1+cl*290+k*2;
    float re=0.f, im=0.f;
    #pragma unroll
    for (int h0=0;h0<16;h0++){
      int p=(r*h0)&127;
      float cr=tw[p*2], ci=tw[p*2+1];
      float sr=Sp[h0*18], si=Sp[h0*18+1];
      re += sr*cr - si*ci;
      im += sr*ci + si*cr;
    }
    float vr = af*re*sc, vi = af*im*sc;
    if (r==0 && (c0+cl)==0) vr += b0;
    S[(i2*11+cl)*2]=vr; S[(i2*11+cl)*2+1]=vi;
  }
  __syncthreads();
  for (int e=threadIdx.x;e<64*11;e+=256){
    int r=e/11, cl=e%11; int c=c0+cl;
    float vr=S[(r*11+cl)*2], vi=S[(r*11+cl)*2+1];
    float* o=X64+((size_t)s*(64*33)+r*33+c)*2; o[0]=vr; o[1]=vi;
    float hr=vr, hi=vi;
    if (c==0 || c==32){
      int pr=(64-r)&63;
      hr=0.5f*(vr+S[(pr*11+cl)*2]);
      hi=0.5f*(vi-S[(pr*11+cl)*2+1]);
    }
    float* oh=X64h+((size_t)s*(64*33)+r*33+c)*2; oh[0]=hr; oh[1]=hi;
  }
}

// ---- UeZYw: units 0..3071 --------------------------------------------------
__device__ __forceinline__ void st_uezyw(int bx, float* sh, const float* X64, const float* X64h,
    const float* qw, const float* qsw, const float* kw, const float* ksw,
    const float* value_w, const float* vsw, const float* vsb,
    const float* proj_w, const float* psw,
    float* Zq, float* Zk, float* Yw, float* Ue){
  if (bx<2048){
    int t=bx>>4, h=bx&15;
    float* Xs = sh;
    float2* xh0 = (float2*)(sh+1092);
    for (int e=threadIdx.x;e<544;e+=256){
      int j=e/17, c=e%17;
      int i2=(j<16)? j : (j+32);
      const float* xp = X64 + ((size_t)t*(64*33) + i2*33 + c)*2;
      Xs[e*2]=xp[0]; Xs[e*2+1]=xp[1];
    }
    if (threadIdx.x<17){
      int j=threadIdx.x;
      int r=(j<=8)? j : j+47;
      const float* hp = X64h + ((size_t)t*(64*33) + r*33)*2;
      xh0[j]=make_float2(hp[0],hp[1]);
    }
    __syncthreads();
    float aq=qsw[h], ak=ksw[h];
    for (int e=threadIdx.x;e<306;e+=256){
      int side=e/153, m=e%153;
      int j=m/9, c=m%9;
      int jj=(j<=8)? j : j+15;
      const float* W = side? kw : qw;
      float a = side? ak : aq;
      float prx=0.f, pry=0.f;
      if (j!=8){
        int jw=(j<8)? j : j-1;
        const float* wp = W + ((size_t)(h*16+jw)*9 + c)*2;
        float xrr=Xs[(jj*17+c)*2], xri=Xs[(jj*17+c)*2+1];
        prx = wp[0]*xrr - wp[1]*xri;
        pry = wp[0]*xri + wp[1]*xrr;
      }
      float Vx=prx, Vy=pry;
      if (c==0){
        int jp = (j==0)? 0 : 17-j;
        float ppx=0.f, ppy=0.f;
        if (jp!=8){
          int jw2=(jp<8)? jp : jp-1;
          const float* wp2 = W + ((size_t)(h*16+jw2)*9)*2;
          int jj2=(jp<=8)? jp : jp+15;
          float x2r=Xs[(jj2*17)*2], x2i=Xs[(jj2*17)*2+1];
          ppx = wp2[0]*x2r - wp2[1]*x2i;
          ppy = wp2[0]*x2i + wp2[1]*x2r;
        }
        Vx = 0.5f*(prx + ppx);
        Vy = 0.5f*(pry - ppy);
      }
      float xmr, xmi;
      if (c==0){ xmr=xh0[j].x; xmi=xh0[j].y; }
      else { xmr=Xs[(jj*17+c)*2]; xmi=Xs[(jj*17+c)*2+1]; }
      float zr = a*xmr + Vx;
      float zi = a*xmi + Vy;
      float wf = (side && c!=0)? 2.f : 1.f;
      float* dst = (side? Zk : Zq) + ((size_t)(t*16+h))*306 + m*2;
      dst[0]=wf*zr; dst[1]=wf*zi;
    }
    int b=t>>5, s=t&31;
    float vw_=vsw[h], vb=vsb[h], pw=psw[h];
    size_t obase = ((size_t)(b*16+h)*32 + s)*1088;
    for (int e=threadIdx.x;e<544;e+=256){
      int j=e/17, c=e%17;
      float xr=Xs[e*2], xi=Xs[e*2+1];
      float wvr=0.f,wvi=0.f;
      if (c<=8 && (j<8||j>=24)){
        int jw=(j<8)? j : (j-16);
        const float* wv = value_w + ((size_t)(h*16+jw)*9 + c)*2;
        wvr=wv[0]; wvi=wv[1];
      }
      float Mr=xr*wvr-xi*wvi, Mi=xr*wvi+xi*wvr;
      float Mhr=Mr, Mhi=Mi;
      if (c==0){
        float Pr2=0.f,Pi2=0.f;
        int jp2=(j==0)?0:((j==16)?-1:32-j);
        if (jp2>=0 && (jp2<8||jp2>=24)){
          int jw2=(jp2<8)? jp2 : (jp2-16);
          const float* wv2=value_w+((size_t)(h*16+jw2)*9)*2;
          float pxr=Xs[(jp2*17)*2], pxi=Xs[(jp2*17)*2+1];
          Pr2=pxr*wv2[0]-pxi*wv2[1];
          Pi2=pxr*wv2[1]+pxi*wv2[0];
        }
        Mhr=0.5f*(Mr+Pr2); Mhi=0.5f*(Mi-Pi2);
      }
      float Yr=vw_*xr+Mhr+((e==0)? vb:0.f);
      float Yi=vw_*xi+Mhi;
      const float* pc=proj_w+((size_t)(h*32+j)*17+c)*2;
      float pr=pc[0], pi=pc[1];
      float* o=Yw+obase+e*2;
      o[0]=pr*Yr-pi*Yi+pw*Mr;
      o[1]=pr*Yi+pi*Yr+pw*Mi;
    }
  } else {
    int u=bx-2048;
    int b=u>>8, rem=u&255, t=rem>>3, sg=rem&7;
    float2* xt=(float2*)sh;
    const float2* src = (const float2*)(X64h + ((size_t)(b*32+t))*4224);
    for (int m=threadIdx.x;m<2112;m+=256){
      int r=m/33, c=m%33;
      bool excl = (c<=8) && (r<=8 || r>=56);
      float w = excl? 0.f : ((c==0||c==32)? 1.f : 2.f);
      float2 v = src[m];
      xt[m]=make_float2(v.x*w, v.y*w);
    }
    __syncthreads();
    float acc[4]={0.f,0.f,0.f,0.f};
    const float2* s0=(const float2*)(X64h + ((size_t)(b*32+sg*4))*4224);
    for (int m=threadIdx.x;m<2112;m+=256){
      float2 a2=xt[m];
      #pragma unroll
      for (int j=0;j<4;j++){
        float2 b2=s0[(size_t)j*2112+m];
        acc[j]+=a2.x*b2.x+a2.y*b2.y;
      }
    }
    for (int j=0;j<4;j++){
      float r=block_reduce1(acc[j]);
      if (threadIdx.x==0) Ue[((size_t)(b*32+t))*32 + sg*4+j]=r;
    }
  }
}

// ---- scores + fused softmax: units 0..127 (zk chunked by 8 for LDS) --------
__device__ __forceinline__ void st_scores(int u, float* sh, const float* Zq, const float* Zk,
                          const float* Ue, const float* qsw, const float* qsb,
                          const float* ksw, const float* ksb, float* P){
  int b=u&3, h=(u>>2)&15, tz=u>>6;
  float2* zq=(float2*)sh;            // [16][154]
  float2* zk=(float2*)(sh+4928);     // [8][154]
  float*  Pl=sh+7392;                // [16][32]
  for (int i=threadIdx.x;i<16*153;i+=256){
    int t=i/153, m=i%153;
    zq[t*154+m]=((const float2*)(Zq + ((size_t)((b*32+tz*16+t)*16+h))*306))[m];
  }
  float aq=qsw[h], ak=ksw[h], bq=qsb[h], bk=ksb[h];
  float aqak=aq*ak;
  int tl=threadIdx.x>>4, sl=threadIdx.x&15;
  for (int ch=0; ch<4; ch++){
    __syncthreads();
    for (int i=threadIdx.x;i<8*153;i+=256){
      int s=i/153, m=i%153;
      zk[s*154+m]=((const float2*)(Zk + ((size_t)((b*32+ch*8+s)*16+h))*306))[m];
    }
    __syncthreads();
    if (sl<8){
      float acc=0.f;
      for (int m=0;m<153;m++){
        float2 a2=zq[tl*154+m], c2=zk[sl*154+m];
        acc += a2.x*c2.x + a2.y*c2.y;
      }
      int s=ch*8+sl;
      float G = aqak*Ue[((size_t)(b*32+tz*16+tl))*32+s] + acc;
      Pl[tl*32+s] = 64.f*(G + bk*zq[tl*154].x + bq*zk[sl*154].x + bq*bk);
    }
  }
  __syncthreads();
  if (threadIdx.x<16){
    int tt=threadIdx.x;
    float mx=-INFINITY;
    for (int s=0;s<32;s++) mx=fmaxf(mx,Pl[tt*32+s]);
    float e[32]; float sum=0.f;
    for (int s=0;s<32;s++){ e[s]=expf(Pl[tt*32+s]-mx); sum+=e[s]; }
    float inv=1.f/sum;
    size_t base=((size_t)(b*16+h)*32+tz*16+tt)*32;
    for (int s=0;s<32;s++) P[base+s]=e[s]*inv;
  }
}

// ---- SfC2 + skipmix: units 0..527 ------------------------------------------
__device__ __forceinline__ void st_sfsk(int bx, float* sh, const float* x, const float* P,
        const float* Yw, const float* pw, const float* vw,
        const float* pstat0, const float* n1g, const float* n1b,
        float* Sfp, float* sk){
  if (bx<272){
    int b=bx/68, rem=bx%68, ec=rem/4, g=rem%4;
    int e0=ec*64, hs0=g*128;
    float (*Pl)[32] = (float(*)[32])sh;
    for (int i=threadIdx.x;i<128*32;i+=256){
      int hsl=i>>5, t=i&31;
      int hs=hs0+hsl, h=hs>>5, s=hs&31;
      Pl[hsl][t]=P[(((size_t)(b*16+h)*32)+t)*32+s];
    }
    __syncthreads();
    int el=threadIdx.x&63, tg=threadIdx.x>>6;
    float acc[8];
    #pragma unroll
    for (int j=0;j<8;j++) acc[j]=0.f;
    const float* Yb = Yw + ((size_t)b*512 + hs0)*1088 + e0 + el;
    #pragma unroll 4
    for (int hsl=0;hsl<128;hsl++){
      float y = Yb[(size_t)hsl*1088];
      #pragma unroll
      for (int j=0;j<8;j++) acc[j] += Pl[hsl][tg*8+j]*y;
    }
    #pragma unroll
    for (int j=0;j<8;j++){
      int t=tg*8+j;
      Sfp[((size_t)(b*32+t)*4+g)*1088 + e0 + el] = acc[j];
    }
  } else {
    int u=bx-272;
    int b=u>>6, rem=u&63, ch=rem>>1, tt=rem&1;
    int pxb=ch*512;
    float* Rs = sh;
    float* cbs = sh+512;
    float* as2 = sh+528;
    float* b0s = sh+560;
    if (threadIdx.x<32){
      float a,b0; affine_from(pstat0, n1g[0], n1b[0], b*32+threadIdx.x, a, b0);
      as2[threadIdx.x]=a; b0s[threadIdx.x]=b0;
    }
    __syncthreads();
    for (int rr=threadIdx.x; rr<512; rr+=256){
      int tl=rr>>5, s=rr&31;
      int t=tt*16+tl;
      float acc=0.f;
      for (int h=0;h<16;h++)
        acc += pw[h]*vw[h]*P[(((size_t)(b*16+h)*32)+t)*32+s];
      Rs[tl*32+s]=acc*as2[s];
      float cb=acc*b0s[s];
      for (int o=16;o>0;o>>=1) cb+=__shfl_down(cb,o,32);
      if (s==0) cbs[tl]=cb;
    }
    __syncthreads();
    float a0[16], a1[16];
    #pragma unroll
    for (int t=0;t<16;t++){ a0[t]=0.f; a1[t]=0.f; }
    for (int s=0;s<32;s++){
      const float* xp = x + ((size_t)(b*32+s))*NPIX + pxb;
      float v0=xp[threadIdx.x], v1=xp[threadIdx.x+256];
      #pragma unroll
      for (int t=0;t<16;t++){ float r=Rs[t*32+s]; a0[t]+=r*v0; a1[t]+=r*v1; }
    }
    #pragma unroll
    for (int t=0;t<16;t++){
      int gt=tt*16+t;
      float cb=cbs[t];
      float* op = sk + ((size_t)(b*32+gt))*NPIX + pxb;
      op[threadIdx.x]=a0[t]+cb; op[threadIdx.x+256]=a1[t]+cb;
    }
  }
}

// ---- field0 (units 0..2047) + raw spec_z (2048..2303) ----------------------
__device__ __forceinline__ void st_f0sp(int bx, float* sh, const float* Sfp,
        const float* sk, const float* x, const float* P, const float* X64,
        const float* pstat0, const float* n1g, const float* n1b,
        const float* pw, const float* vw,
        const float* psw, const float* vsb, const float* psb,
        float* zf, float* pstatA, float* sp){
  if (bx<2048){
    int bt=bx>>4, slab=bx&15;
    float* Ss=sh; float* T=sh+1088; float* tw=sh+1360;
    for (int i=threadIdx.x;i<1088;i+=256){
      const float* sp4 = Sfp + (size_t)bt*4352 + i;
      Ss[i] = sp4[0]+sp4[1088]+sp4[2176]+sp4[3264];
    }
    for (int q=threadIdx.x;q<128;q+=256){ float sn,cs; sincosf((2.f*PI_F/128.f)*(float)q,&sn,&cs); tw[q*2]=cs; tw[q*2+1]=sn; }
    __syncthreads();
    int h0 = slab*8;
    for (int e=threadIdx.x;e<136;e+=256){
      int hl=e/17, c=e%17; int h=h0+hl;
      float re=0.f, im=0.f;
      for (int j=0;j<32;j++){
        int r=(j<16)? j : (j+96);
        int p=(r*h)&127;
        float cs=tw[p*2], sn=tw[p*2+1];
        float ar=Ss[(j*17+c)*2], ai=Ss[(j*17+c)*2+1];
        re += ar*cs - ai*sn;
        im += ar*sn + ai*cs;
      }
      T[e*2]=re; T[e*2+1]=im;
    }
    __syncthreads();
    size_t base = (size_t)bt*NPIX + h0*128;
    float Cb = psb[0];
    for (int hh=0;hh<16;hh++) Cb += psw[hh]*vsb[hh];
    int w=threadIdx.x&127, hl0=threadIdx.x>>7;
    float cw[16], swt[16];
    #pragma unroll
    for (int c=0;c<16;c++){ int p=((c+1)*w)&127; cw[c]=tw[p*2]; swt[c]=tw[p*2+1]; }
    float sum=0.f, sq=0.f;
    #pragma unroll
    for (int pp=0;pp<4;pp++){
      int hl=hl0+2*pp;
      const float2* Th=(const float2*)(T+hl*34);
      float v=Th[0].x;
      #pragma unroll
      for (int c=0;c<16;c++){ float2 th=Th[c+1]; v += 2.f*(th.x*cw[c] - th.y*swt[c]); }
      int pos=hl*128+w;
      float val = v + sk[base+pos] + x[base+pos] + Cb;
      zf[base+pos]=val; sum+=val; sq+=val*val;
    }
    block_reduce2(sum,sq);
    if (threadIdx.x==0){ float* o=pstatA+((size_t)bt*16+slab)*2; o[0]=sum; o[1]=sq; }
  } else {
    int u=bx-2048;
    int bt=u>>1, ec=u&1; int b=bt>>5, t=bt&31;
    float* Sfl=sh; float* Rs=sh+1088;
    if (threadIdx.x<32){
      int s=threadIdx.x; float acc=0.f;
      for (int h=0;h<16;h++)
        acc += pw[h]*vw[h]*P[(((size_t)(b*16+h)*32)+t)*32+s];
      Rs[s]=acc;
    }
    for (int i=threadIdx.x;i<1088;i+=256){
      const float* sp4 = Sfp + (size_t)bt*4352 + i;
      Sfl[i]=sp4[0]+sp4[1088]+sp4[2176]+sp4[3264];
    }
    __syncthreads();
    float a_t,b0_t; affine_from(pstat0,n1g[0],n1b[0],bt,a_t,b0_t);
    float Cb=psb[0];
    for (int h=0;h<16;h++) Cb+=psw[h]*vsb[h];
    float inva=1.f/a_t;
    int e1=ec*272, e2=e1+272;
    for (int e=e1+threadIdx.x;e<e2;e+=256){
      int j=e/17, c=e%17;
      float sr=Sfl[e*2], si=Sfl[e*2+1];
      if (c==0){
        if (j==0){ si=0.f; }
        else if (j==16){ sr*=0.5f; si*=0.5f; }
        else { int jp=32-j; sr=0.5f*(sr+Sfl[jp*34]); si=0.5f*(si-Sfl[jp*34+1]); }
      }
      int i2=(j<16)? j : (j+32);
      float re=0.f, im=0.f;
      const float* xb = X64 + ((size_t)(b*32)*(64*33) + i2*33 + c)*2;
      for (int s=0;s<32;s++){
        const float* xp = xb + (size_t)s*(64*33)*2;
        float r=Rs[s];
        re += r*xp[0]; im += r*xp[1];
      }
      const float* xt = X64 + ((size_t)bt*(64*33) + i2*33 + c)*2;
      re += inva*xt[0]; im += inva*xt[1];
      float zr=sr+re, zi=si+im;
      if (e==0) zr += Cb - b0_t*inva;
      sp[((size_t)bt*544+e)*2]=zr; sp[((size_t)bt*544+e)*2+1]=zi;
    }
  }
}

// ---- mixer1 field: units 0..2047 (bt=u&127, slab=u>>7) ---------------------
__device__ __forceinline__ void st_field1(int u, float* sh, const float* sp, const float* wm,
        const float* pstatA, const float* ag, const float* n2g, const float* n2b,
        float* fd1, float* pstatB){
  int bt=u&127, slab=u>>7;
  float* Ss=sh; float* T=sh+1088; float* tw=sh+1360;
  float muZ,aA,a0;
  scalA_from(pstatA, ag[0], n2g[0], bt, muZ, aA, a0);
  float d0 = n2b[0] - muZ*a0;
  for (int e=threadIdx.x;e<544;e+=256){
    float xr=a0*sp[((size_t)bt*544+e)*2] + ((e==0)? d0 : 0.f);
    float xi=a0*sp[((size_t)bt*544+e)*2+1];
    float wr=wm[e*2], wi=wm[e*2+1];
    Ss[e*2]=xr*wr-xi*wi; Ss[e*2+1]=xr*wi+xi*wr;
  }
  for (int q=threadIdx.x;q<128;q+=256){ float sn,cs; sincosf((2.f*PI_F/128.f)*(float)q,&sn,&cs); tw[q*2]=cs; tw[q*2+1]=sn; }
  __syncthreads();
  int h0 = slab*8;
  for (int e=threadIdx.x;e<8*17;e+=256){
    int hl=e/17, c=e%17; int h=h0+hl;
    float re=0.f, im=0.f;
    for (int j=0;j<32;j++){
      int r=(j<16)? j : (j+96);
      int p=(r*h)&127;
      float cs=tw[p*2], sn=tw[p*2+1];
      float ar=Ss[(j*17+c)*2], ai=Ss[(j*17+c)*2+1];
      re += ar*cs - ai*sn;
      im += ar*sn + ai*cs;
    }
    T[e*2]=re; T[e*2+1]=im;
  }
  __syncthreads();
  size_t base = (size_t)bt*NPIX + h0*128;
  int w=threadIdx.x&127, hl0=threadIdx.x>>7;
  float cw[16], swt[16];
  #pragma unroll
  for (int c=0;c<16;c++){ int p=((c+1)*w)&127; cw[c]=tw[p*2]; swt[c]=tw[p*2+1]; }
  float sum=0.f, sq=0.f;
  #pragma unroll
  for (int pp=0;pp<4;pp++){
    int hl=hl0+2*pp;
    const float2* Th=(const float2*)(T+hl*34);
    float v=Th[0].x;
    #pragma unroll
    for (int c=0;c<16;c++){ float2 th=Th[c+1]; v += 2.f*(th.x*cw[c] - th.y*swt[c]); }
    int pos=hl*128+w;
    fd1[base+pos]=v; sum+=v; sq+=v*v;
  }
  block_reduce2(sum,sq);
  if (threadIdx.x==0){ float* o=pstatB+((size_t)bt*16+slab)*2; o[0]=sum; o[1]=sq; }
}

// ---- column DFT of m1 (radix 16x8): units 0..1023 --------------------------
__device__ __forceinline__ void st_colA1(int u, float* sh, const float* f1, const float* z,
        const float* pstatA, const float* pstatB,
        const float* ag, const float* n2g, const float* mng1, const float* n2b,
        const float* mnb1, const float* msw1, const float* msb1, float* A){
  float* rows=sh; float* S1=sh+2048; float* tw=sh+4640;
  int grow = u*16;
  int t = grow>>7;
  float muZ,aA,a0;
  scalA_from(pstatA, ag[0], n2g[0], t, muZ, aA, a0);
  float b2 = n2b[0];
  float mu1,c1;
  scalB_from(pstatB, mng1[0], t, mu1, c1);
  float nb=mnb1[0], sw=msw1[0], sb=msb1[0];
  for (int i=threadIdx.x;i<2048;i+=256){
    size_t gi=(size_t)grow*128+i;
    float m0v=(z[gi]-muZ)*a0+b2;
    float y=(f1[gi]-mu1)*c1+nb + m0v*sw + sb;
    rows[i]=gelu_f(y);
  }
  for (int q=threadIdx.x;q<128;q+=256){ float sn,cs; sincosf(-(2.f*PI_F/128.f)*(float)q,&sn,&cs); tw[q*2]=cs; tw[q*2+1]=sn; }
  __syncthreads();
  for (int e=threadIdx.x;e<1280;e+=256){
    int r=e/80, q=e%80, w0=q/5, k=q%5;
    const float* y=rows+r*128+w0;
    float re=0.f, im=0.f;
    #pragma unroll
    for (int w1=0;w1<8;w1++){
      int p=(16*k*w1)&127;
      float v=y[w1*16];
      re+=v*tw[p*2]; im+=v*tw[p*2+1];
    }
    float* o=S1+r*162+q*2; o[0]=re; o[1]=im;
  }
  __syncthreads();
  for (int e=threadIdx.x;e<272;e+=256){
    int r=e/17, c=e%17;
    int m=c&7; int ks=m; float sg=1.f;
    if (m>4){ ks=8-m; sg=-1.f; }
    const float* Sp=S1+r*162+ks*2;
    float re=0.f, im=0.f;
    #pragma unroll
    for (int w0=0;w0<16;w0++){
      int p=(c*w0)&127;
      float cr=tw[p*2], ci=tw[p*2+1];
      float sr=Sp[w0*10], si=sg*Sp[w0*10+1];
      re += sr*cr - si*ci;
      im += sr*ci + si*cr;
    }
    float* o=A+((size_t)(grow+r)*17+c)*2; o[0]=re; o[1]=im;
  }
}

// ---- forward 32x17 modes (radix 16x8): units 0..511 (s=u&127, cg2=u>>7) ----
__device__ __forceinline__ void st_row32(int u, float* sh, const float* A, float* spec){
  int s=u&127, cg2=u>>7;
  int c0 = (cg2==0)? 0 : (1+cg2*4);
  int nc = (cg2==0)? 5 : 4;
  float* a=sh;          // 1280
  float* S1=sh+1280;    // 1450
  float* tw=sh+2730;    // 256
  for (int i=threadIdx.x;i<128*nc*2;i+=256){
    int r=i/(2*nc), q=i%(2*nc);
    a[(r*5+(q>>1))*2+(q&1)] = A[((size_t)(s*128+r)*17 + c0)*2 + q];
  }
  for (int q=threadIdx.x;q<128;q+=256){ float sn,cs; sincosf(-(2.f*PI_F/128.f)*(float)q,&sn,&cs); tw[q*2]=cs; tw[q*2+1]=sn; }
  __syncthreads();
  for (int e=threadIdx.x;e<nc*128;e+=256){
    int cl=e>>7, q=e&127, h0=q>>3, k=q&7;
    float re=0.f, im=0.f;
    #pragma unroll
    for (int h1=0;h1<8;h1++){
      int p=(16*k*h1)&127;
      float cr=tw[p*2], ci=tw[p*2+1];
      const float* ap=a+((h0+16*h1)*5+cl)*2;
      float ar=ap[0], ai=ap[1];
      re += ar*cr - ai*ci;
      im += ar*ci + ai*cr;
    }
    float* o=S1+cl*290+h0*18+k*2; o[0]=re; o[1]=im;
  }
  __syncthreads();
  const float sc=1.f/16384.f;
  for (int e=threadIdx.x;e<32*nc;e+=256){
    int j=e/nc, cl=e%nc;
    int r=(j<16)? j : (j+96);
    int k=r&7;
    const float* Sp=S1+cl*290+k*2;
    float re=0.f,im=0.f;
    #pragma unroll
    for (int h0=0;h0<16;h0++){
      int p=(r*h0)&127;
      float cr=tw[p*2], ci=tw[p*2+1];
      float sr=Sp[h0*18], si=Sp[h0*18+1];
      re += sr*cr - si*ci;
      im += sr*ci + si*cr;
    }
    float* o=spec+((size_t)s*544 + j*17 + c0+cl)*2;
    o[0]=re*sc; o[1]=im*sc;
  }
}

// ---- mixer2 field: units 0..2047 -------------------------------------------
__device__ __forceinline__ void st_field2(int u, float* sh, const float* sp2, const float* wm,
        const float* f1, const float* z, const float* pstatA, const float* pstatB,
        const float* ag, const float* n2g, const float* mng1, const float* n2b,
        const float* mnb1, const float* msw1, const float* msb1,
        float* fd2, float* pstatC){
  int bt=u&127, slab=u>>7;
  float* Ss=sh; float* T=sh+1088; float* tw=sh+1360;
  for (int e=threadIdx.x;e<544;e+=256){
    float xr=sp2[((size_t)bt*544+e)*2], xi=sp2[((size_t)bt*544+e)*2+1];
    float wr=wm[e*2], wi=wm[e*2+1];
    Ss[e*2]=xr*wr-xi*wi; Ss[e*2+1]=xr*wi+xi*wr;
  }
  for (int q=threadIdx.x;q<128;q+=256){ float sn,cs; sincosf((2.f*PI_F/128.f)*(float)q,&sn,&cs); tw[q*2]=cs; tw[q*2+1]=sn; }
  __syncthreads();
  int h0 = slab*8;
  for (int e=threadIdx.x;e<8*17;e+=256){
    int hl=e/17, c=e%17; int h=h0+hl;
    float re=0.f, im=0.f;
    for (int j=0;j<32;j++){
      int r=(j<16)? j : (j+96);
      int p=(r*h)&127;
      float cs=tw[p*2], sn=tw[p*2+1];
      float ar=Ss[(j*17+c)*2], ai=Ss[(j*17+c)*2+1];
      re += ar*cs - ai*sn;
      im += ar*sn + ai*cs;
    }
    T[e*2]=re; T[e*2+1]=im;
  }
  __syncthreads();
  size_t base = (size_t)bt*NPIX + h0*128;
  float muZ,aA,a0,mu1,c1;
  scalA_from(pstatA, ag[0], n2g[0], bt, muZ, aA, a0);
  scalB_from(pstatB, mng1[0], bt, mu1, c1);
  float b2=n2b[0], nb1=mnb1[0], sw1=msw1[0], sb1=msb1[0];
  int w=threadIdx.x&127, hl0=threadIdx.x>>7;
  float cw[16], swt[16];
  #pragma unroll
  for (int c=0;c<16;c++){ int p=((c+1)*w)&127; cw[c]=tw[p*2]; swt[c]=tw[p*2+1]; }
  float s_f=0.f,s_fsq=0.f,s_m=0.f,s_msq=0.f,s_x=0.f;
  #pragma unroll
  for (int pp=0;pp<4;pp++){
    int hl=hl0+2*pp;
    const float2* Th=(const float2*)(T+hl*34);
    float v=Th[0].x;
    #pragma unroll
    for (int c=0;c<16;c++){ float2 th=Th[c+1]; v += 2.f*(th.x*cw[c] - th.y*swt[c]); }
    int pos=hl*128+w;
    size_t gi=base+pos;
    float m0v=(z[gi]-muZ)*a0+b2;
    float y=(f1[gi]-mu1)*c1+nb1 + m0v*sw1 + sb1;
    float m1v=gelu_f(y);
    fd2[gi]=v;
    s_f+=v; s_fsq+=v*v; s_m+=m1v; s_msq+=m1v*m1v; s_x+=v*m1v;
  }
  block_reduce2(s_f,s_fsq);
  block_reduce2(s_m,s_msq);
  s_x = block_reduce1(s_x);
  if (threadIdx.x==0){
    float* o=pstatC+((size_t)bt*16+slab)*5;
    o[0]=s_f; o[1]=s_fsq; o[2]=s_m; o[3]=s_msq; o[4]=s_x;
  }
}

// ---- final: units 0..2047 --------------------------------------------------
__device__ __forceinline__ void st_final(int u, const float* z, const float* f1, const float* f2,
        const float* pstatA, const float* pstatB, const float* pstatC,
        const float* ag, const float* n2g, const float* mng1, const float* mng2, const float* outg,
        const float* ab, const float* n2b, const float* mnb1, const float* msw1, const float* msb1,
        const float* mnb2, const float* msw2, const float* msb2, const float* outb, float* out){
  int bt=u&127, slab=u>>7;
  float muZ,aA,a0,mu1,c1,mu2f,c2,mu3,c3;
  scalA_from(pstatA, ag[0], n2g[0], bt, muZ, aA, a0);
  scalB_from(pstatB, mng1[0], bt, mu1, c1);
  float sw2=msw2[0], K=mnb2[0]+msb2[0];
  scalC_from(pstatC, mng2[0], K, sw2, outg[0], bt, mu2f, c2, mu3, c3);
  float b1=ab[0], b2=n2b[0], nb1=mnb1[0], sw1=msw1[0], sb1=msb1[0];
  float nb2=mnb2[0], sb2=msb2[0], bo=outb[0];
  size_t base=(size_t)bt*NPIX + (size_t)slab*1024;
  for (int i=threadIdx.x;i<1024;i+=256){
    size_t gi=base+i;
    float zv=z[gi];
    float m0v=(zv-muZ)*a0+b2;
    float a2v=(zv-muZ)*aA+b1;
    float y=(f1[gi]-mu1)*c1+nb1 + m0v*sw1 + sb1;
    float m1v=gelu_f(y);
    float m2v=(f2[gi]-mu2f)*c2+nb2 + m1v*sw2 + sb2;
    out[gi]=(m2v-mu3)*c3+bo+a2v;
  }
}

// ============================ mega kernel (software barrier) ================
struct MP {
  const float *x,*key_w,*key_sw,*key_sb,*query_w,*query_sw,*query_sb,
    *value_w,*value_sw,*value_sb,*proj_w,*proj_sw,*proj_sb,
    *norm1_g,*norm1_b,*attn_g,*attn_b,*norm2_g,*norm2_b,
    *mw1,*msw1,*msb1,*mng1,*mnb1,*mw2,*msw2,*msb2,*mng2,*mnb2,*outg,*outb;
  float *A,*X64,*X64h,*Zq,*Zk,*Ue,*P,*Yw,*Sfp,*sk,*zf,*fd1,*fd2,*sp,*sp2,
    *pstat0,*pstatA,*pstatB,*pstatC,*out;
};

__global__ __launch_bounds__(256,4) void k_megasw(MP p, unsigned* bars){
  __shared__ float sh[7920];
  for (int u=blockIdx.x;u<2048;u+=NBLK){ __syncthreads(); st_scol(u,sh,p.x,p.A,p.pstat0); }
  gbar(bars+0);
  if (blockIdx.x<384) st_row64(blockIdx.x,sh,p.A,p.pstat0,p.norm1_g,p.norm1_b,p.X64,p.X64h);
  gbar(bars+1);
  for (int u=blockIdx.x;u<3072;u+=NBLK){ __syncthreads(); st_uezyw(u,sh,p.X64,p.X64h,p.query_w,p.query_sw,p.key_w,p.key_sw,p.value_w,p.value_sw,p.value_sb,p.proj_w,p.proj_sw,p.Zq,p.Zk,p.Yw,p.Ue); }
  gbar(bars+2);
  if (blockIdx.x<128) st_scores(blockIdx.x,sh,p.Zq,p.Zk,p.Ue,p.query_sw,p.query_sb,p.key_sw,p.key_sb,p.P);
  gbar(bars+3);
  if (blockIdx.x<528) st_sfsk(blockIdx.x,sh,p.x,p.P,p.Yw,p.proj_sw,p.value_sw,p.pstat0,p.norm1_g,p.norm1_b,p.Sfp,p.sk);
  gbar(bars+4);
  for (int u=blockIdx.x;u<2304;u+=NBLK){ __syncthreads(); st_f0sp(u,sh,p.Sfp,p.sk,p.x,p.P,p.X64,p.pstat0,p.norm1_g,p.norm1_b,p.proj_sw,p.value_sw,p.proj_sw,p.value_sb,p.proj_sb,p.zf,p.pstatA,p.sp); }
  gbar(bars+5);
  for (int u=blockIdx.x;u<2048;u+=NBLK){ __syncthreads(); st_field1(u,sh,p.sp,p.mw1,p.pstatA,p.attn_g,p.norm2_g,p.norm2_b,p.fd1,p.pstatB); }
  gbar(bars+6);
  st_colA1(blockIdx.x,sh,p.fd1,p.zf,p.pstatA,p.pstatB,p.attn_g,p.norm2_g,p.mng1,p.norm2_b,p.mnb1,p.msw1,p.msb1,p.A);
  gbar(bars+7);
  if (blockIdx.x<512) st_row32(blockIdx.x,sh,p.A,p.sp2);
  gbar(bars+8);
  for (int u=blockIdx.x;u<2048;u+=NBLK){ __syncthreads(); st_field2(u,sh,p.sp2,p.mw2,p.fd1,p.zf,p.pstatA,p.pstatB,p.attn_g,p.norm2_g,p.mng1,p.norm2_b,p.mnb1,p.msw1,p.msb1,p.fd2,p.pstatC); }
  gbar(bars+9);
  for (int u=blockIdx.x;u<2048;u+=NBLK){ st_final(u,p.zf,p.fd1,p.fd2,p.pstatA,p.pstatB,p.pstatC,p.attn_g,p.norm2_g,p.mng1,p.mng2,p.outg,p.attn_b,p.norm2_b,p.mnb1,p.msw1,p.msb1,p.mnb2,p.msw2,p.msb2,p.outb,p.out); }
}

// ============================ fallback wrappers =============================
__global__ __launch_bounds__(256) void k_scol(const float* x, float* A, float* pstat){
  __shared__ float sh[4896];
  st_scol(blockIdx.x, sh, x, A, pstat);
}
__global__ __launch_bounds__(256) void k_rowfft64(const float* A, const float* pstat0,
    const float* n1g, const float* n1b, float* X64, float* X64h){
  __shared__ float sh[7670];
  st_row64(blockIdx.x + 128*blockIdx.y, sh, A, pstat0, n1g, n1b, X64, X64h);
}
__global__ __launch_bounds__(256) void k_UeZYw(const float* X64, const float* X64h,
    const float* qw, const float* qsw, const float* kw, const float* ksw,
    const float* value_w, const float* vsw, const float* vsb,
    const float* proj_w, const float* psw,
    float* Zq, float* Zk, float* Yw, float* Ue){
  __shared__ float sh[4224];
  st_uezyw(blockIdx.x, sh, X64, X64h, qw, qsw, kw, ksw, value_w, vsw, vsb, proj_w, psw, Zq, Zk, Yw, Ue);
}
__global__ __launch_bounds__(256) void k_scores2(const float* Zq, const float* Zk,
    const float* Ue, const float* qsw, const float* qsb,
    const float* ksw, const float* ksb, float* P){
  __shared__ float sh[7920];
  st_scores(blockIdx.x + 4*blockIdx.y + 64*blockIdx.z, sh, Zq, Zk, Ue, qsw, qsb, ksw, ksb, P);
}
__global__ __launch_bounds__(256) void k_SfSk(const float* x, const float* P, const float* Yw,
    const float* pw, const float* vw, const float* pstat0, const float* n1g, const float* n1b,
    float* Sfp, float* sk){
  __shared__ float sh[4096];
  st_sfsk(blockIdx.x, sh, x, P, Yw, pw, vw, pstat0, n1g, n1b, Sfp, sk);
}
__global__ __launch_bounds__(256) void k_f0sp(const float* Sfp, const float* sk, const float* x,
    const float* P, const float* X64, const float* pstat0,
    const float* n1g, const float* n1b, const float* pw, const float* vw,
    const float* psw, const float* vsb, const float* psb,
    float* zf, float* pstatA, float* sp){
  __shared__ float sh[1616];
  st_f0sp(blockIdx.x, sh, Sfp, sk, x, P, X64, pstat0, n1g, n1b, pw, vw, psw, vsb, psb, zf, pstatA, sp);
}
__global__ __launch_bounds__(256) void k_field1(const float* sp, const float* wm,
    const float* pstatA, const float* ag, const float* n2g, const float* n2b,
    float* fd1, float* pstatB){
  __shared__ float sh[1616];
  st_field1(blockIdx.x + 128*blockIdx.y, sh, sp, wm, pstatA, ag, n2g, n2b, fd1, pstatB);
}
__global__ __launch_bounds__(256) void k_colA1(const float* f1, const float* z,
    const float* pstatA, const float* pstatB,
    const float* ag, const float* n2g, const float* mng1, const float* n2b,
    const float* mnb1, const float* msw1, const float* msb1, float* A){
  __shared__ float sh[4896];
  st_colA1(blockIdx.x, sh, f1, z, pstatA, pstatB, ag, n2g, mng1, n2b, mnb1, msw1, msb1, A);
}
__global__ __launch_bounds__(256) void k_rowfft32(const float* A, float* spec){
  __shared__ float sh[2986];
  st_row32(blockIdx.x + 128*blockIdx.y, sh, A, spec);
}
__global__ __launch_bounds__(256) void k_field2(const float* sp2, const float* wm,
    const float* f1, const float* z, const float* pstatA, const float* pstatB,
    const float* ag, const float* n2g, const float* mng1, const float* n2b,
    const float* mnb1, const float* msw1, const float* msb1,
    float* fd2, float* pstatC){
  __shared__ float sh[1616];
  st_field2(blockIdx.x + 128*blockIdx.y, sh, sp2, wm, f1, z, pstatA, pstatB, ag, n2g, mng1, n2b, mnb1, msw1, msb1, fd2, pstatC);
}
__global__ __launch_bounds__(256) void k_final2(const float* z, const float* f1, const float* f2,
    const float* pstatA, const float* pstatB, const float* pstatC,
    const float* ag, const float* n2g, const float* mng1, const float* mng2, const float* outg,
    const float* ab, const float* n2b, const float* mnb1, const float* msw1, const float* msb1,
    const float* mnb2, const float* msw2, const float* msb2, const float* outb, float* out){
  st_final(blockIdx.x + 128*blockIdx.y, z, f1, f2, pstatA, pstatB, pstatC,
           ag, n2g, mng1, mng2, outg, ab, n2b, mnb1, msw1, msb1, mnb2, msw2, msb2, outb, out);
}

extern "C" void kernel_launch(void* const* d_in, const int* in_sizes, int n_in,
                              void* d_out, int out_size, void* d_ws, size_t ws_size,
                              hipStream_t stream){
  const float* x        = (const float*)d_in[0];
  const float* key_w    = (const float*)d_in[1];
  const float* key_sw   = (const float*)d_in[2];
  const float* key_sb   = (const float*)d_in[3];
  const float* query_w  = (const float*)d_in[4];
  const float* query_sw = (const float*)d_in[5];
  const float* query_sb = (const float*)d_in[6];
  const float* value_w  = (const float*)d_in[7];
  const float* value_sw = (const float*)d_in[8];
  const float* value_sb = (const float*)d_in[9];
  const float* proj_w   = (const float*)d_in[10];
  const float* proj_sw  = (const float*)d_in[11];
  const float* proj_sb  = (const float*)d_in[12];
  const float* norm1_g  = (const float*)d_in[13];
  const float* norm1_b  = (const float*)d_in[14];
  const float* attn_g   = (const float*)d_in[15];
  const float* attn_b   = (const float*)d_in[16];
  const float* norm2_g  = (const float*)d_in[17];
  const float* norm2_b  = (const float*)d_in[18];
  const float* mw1      = (const float*)d_in[19];
  const float* msw1     = (const float*)d_in[20];
  const float* msb1     = (const float*)d_in[21];
  const float* mng1     = (const float*)d_in[22];
  const float* mnb1     = (const float*)d_in[23];
  const float* mw2      = (const float*)d_in[24];
  const float* msw2     = (const float*)d_in[25];
  const float* msb2     = (const float*)d_in[26];
  const float* mng2     = (const float*)d_in[27];
  const float* mnb2     = (const float*)d_in[28];
  const float* outg     = (const float*)d_in[29];
  const float* outb     = (const float*)d_in[30];
  float* out = (float*)d_out;
  float* ws  = (float*)d_ws;

  size_t off=0;
  float* A   = ws + off; off += (size_t)128*128*33*2;
  float* X64 = ws + off; off += (size_t)128*64*33*2;
  float* X64h= ws + off; off += (size_t)128*64*33*2;
  float* Zq  = ws + off; off += (size_t)128*16*306;
  float* Zk  = ws + off; off += (size_t)128*16*306;
  float* Ue  = ws + off; off += (size_t)4*32*32;
  float* P   = ws + off; off += (size_t)4*16*32*32;
  float* Yw  = ws + off; off += (size_t)2048*1088;
  float* Sfp = ws + off; off += (size_t)128*4*1088;
  float* sk  = ws + off; off += (size_t)128*16384;
  float* zf  = ws + off; off += (size_t)128*16384;
  float* fd1 = ws + off; off += (size_t)128*16384;
  float* fd2 = ws + off; off += (size_t)128*16384;
  float* sp  = ws + off; off += (size_t)128*544*2;
  float* sp2 = ws + off; off += (size_t)128*544*2;
  float* pstat0 = ws + off; off += (size_t)128*8*2;
  float* pstatA = ws + off; off += (size_t)128*16*2;
  float* pstatB = ws + off; off += (size_t)128*16*2;
  float* pstatC = ws + off; off += (size_t)128*16*5;
  unsigned* bars = (unsigned*)(ws + off); off += 16;

  MP p;
  p.x=x; p.key_w=key_w; p.key_sw=key_sw; p.key_sb=key_sb;
  p.query_w=query_w; p.query_sw=query_sw; p.query_sb=query_sb;
  p.value_w=value_w; p.value_sw=value_sw; p.value_sb=value_sb;
  p.proj_w=proj_w; p.proj_sw=proj_sw; p.proj_sb=proj_sb;
  p.norm1_g=norm1_g; p.norm1_b=norm1_b; p.attn_g=attn_g; p.attn_b=attn_b;
  p.norm2_g=norm2_g; p.norm2_b=norm2_b;
  p.mw1=mw1; p.msw1=msw1; p.msb1=msb1; p.mng1=mng1; p.mnb1=mnb1;
  p.mw2=mw2; p.msw2=msw2; p.msb2=msb2; p.mng2=mng2; p.mnb2=mnb2;
  p.outg=outg; p.outb=outb;
  p.A=A; p.X64=X64; p.X64h=X64h; p.Zq=Zq; p.Zk=Zk; p.Ue=Ue; p.P=P; p.Yw=Yw;
  p.Sfp=Sfp; p.sk=sk; p.zf=zf; p.fd1=fd1; p.fd2=fd2; p.sp=sp; p.sp2=sp2;
  p.pstat0=pstat0; p.pstatA=pstatA; p.pstatB=pstatB; p.pstatC=pstatC; p.out=out;

  // residency pre-check: only use the software-barrier path if 4 blocks/CU fit
  static int mega_ok = -1;
  if (mega_ok < 0){
    int nb = 0;
    hipError_t qe = hipOccupancyMaxActiveBlocksPerMultiprocessor(&nb, k_megasw, 256, 0);
    mega_ok = (qe == hipSuccess && nb >= 4) ? 1 : 0;
  }

  if (mega_ok == 1){
    hipMemsetAsync(bars, 0, 16*sizeof(unsigned), stream);
    k_megasw<<<dim3(1024),dim3(256),0,stream>>>(p, bars);
  } else {
    k_scol<<<2048,256,0,stream>>>(x, A, pstat0);
    k_rowfft64<<<dim3(128,3),256,0,stream>>>(A, pstat0, norm1_g, norm1_b, X64, X64h);
    k_UeZYw<<<3072,256,0,stream>>>(X64, X64h, query_w, query_sw, key_w, key_sw,
        value_w, value_sw, value_sb, proj_w, proj_sw, Zq, Zk, Yw, Ue);
    k_scores2<<<dim3(4,16,2),256,0,stream>>>(Zq, Zk, Ue, query_sw, query_sb, key_sw, key_sb, P);
    k_SfSk<<<528,256,0,stream>>>(x, P, Yw, proj_sw, value_sw, pstat0, norm1_g, norm1_b, Sfp, sk);
    k_f0sp<<<2304,256,0,stream>>>(Sfp, sk, x, P, X64, pstat0, norm1_g, norm1_b,
        proj_sw, value_sw, proj_sw, value_sb, proj_sb, zf, pstatA, sp);
    k_field1<<<dim3(128,16),256,0,stream>>>(sp, mw1, pstatA, attn_g, norm2_g, norm2_b, fd1, pstatB);
    k_colA1<<<1024,256,0,stream>>>(fd1, zf, pstatA, pstatB, attn_g, norm2_g, mng1,
        norm2_b, mnb1, msw1, msb1, A);
    k_rowfft32<<<dim3(128,4),256,0,stream>>>(A, sp2);
    k_field2<<<dim3(128,16),256,0,stream>>>(sp2, mw2, fd1, zf, pstatA, pstatB,
        attn_g, norm2_g, mng1, norm2_b, mnb1, msw1, msb1, fd2, pstatC);
    k_final2<<<dim3(128,16),256,0,stream>>>(zf, fd1, fd2, pstatA, pstatB, pstatC,
        attn_g, norm2_g, mng1, mng2, outg, attn_b, norm2_b,
        mnb1, msw1, msb1, mnb2, msw2, msb2, outb, out);
  }
}